// Round 11
// baseline (1124.918 us; speedup 1.0000x reference)
//
#include <hip/hip_runtime.h>
#include <math.h>

#define B_ 1024
#define T_ 15
#define E_ 128
#define H_ 1024
#define L_ 128
#define V_ 21

typedef unsigned char u8;
typedef long i64;
typedef __attribute__((ext_vector_type(8))) short bf16x8;
typedef __attribute__((ext_vector_type(4))) float f32x4;

__device__ __forceinline__ float sigf(float x) { return 1.0f / (1.0f + __expf(-x)); }
__device__ __forceinline__ float tanhfast(float x) {
    float t = __expf(-2.0f * fabsf(x));
    float r = (1.0f - t) / (1.0f + t);
    return copysignf(r, x);
}

__device__ __forceinline__ ushort f2bf(float f) {
    unsigned u = __float_as_uint(f);
    u += 0x7fffu + ((u >> 16) & 1u);
    return (ushort)(u >> 16);
}
__device__ __forceinline__ float bf2f(ushort u) {
    return __uint_as_float((unsigned)u << 16);
}

// f32 -> OCP e4m3fn, RNE, saturate to 448
__device__ __forceinline__ u8 f2e4(float x) {
    unsigned u = __float_as_uint(x);
    u8 s = (u >> 24) & 0x80;
    float ax = fminf(fabsf(x), 448.0f);
    unsigned ua = __float_as_uint(ax);
    int e = (int)(ua >> 23) - 127;
    if (e < -6) {
        int q = (int)rintf(ax * 512.0f);
        return s | (u8)q;
    }
    unsigned m = ua & 0x7FFFFFu;
    unsigned lsb = (m >> 20) & 1u;
    m += 0x7FFFFu + lsb;
    if (m >> 23) { m = 0; e += 1; }
    if (e > 8) return s | 0x7E;
    return s | (u8)(((e + 7) << 3) | (m >> 20));
}

__device__ __forceinline__ void gl_lds16(const void* g, void* l) {
    __builtin_amdgcn_global_load_lds(
        (const __attribute__((address_space(1))) void*)g,
        (__attribute__((address_space(3))) void*)l, 16, 0, 0);
}

// ========== fp8 64x128 MFMA GEMM, BK=64, RING-3 + counted vmcnt ==========
// R10 geometry (4 waves, wave 32x64 = acc[2][4], fp8 16x16x32). NEW: 3-buffer
// ring; per iter: wait OWN vmcnt(3) [tile t's 3 loads done, tile t+1 in
// flight] -> s_barrier [block-wide: tile t ready] -> STAGE(t+2) into the
// buffer of tile t-1 [safe: all waves consumed t-1 before this barrier] ->
// ds_read + MFMA tile t. Loads now survive one barrier: ~6KB in flight per
// wave vs 0 in the drain-every-iter R10 loop. LDS 36KB -> still 4 blk/CU.
// (R5/R6's ring FETCH-doubling was the bf16 128-tile L2 overflow — per-XCD
// working set was 4.7MB > 4MB; here it is ~2.9MB.)
template <class ALd, class WLd, class Epi>
__global__ __launch_bounds__(256, 4) void gemm_f8(ALd al, WLd wl, Epi ep) {
    __shared__ u8 As[3 * 4096];
    __shared__ u8 Ws[3 * 8192];
    const int tid = threadIdx.x;
    const int lane = tid & 63;
    const int w = tid >> 6;
    const int wr = w >> 1, wc = w & 1;
    const int bn = blockIdx.x * 128 + al.bn0;
    const int bm = blockIdx.y * 64;
    const int lrow = lane >> 1;
    const int lcolb = (lane & 1) * 16;
    const int K = al.kdim(bn);
    const int nt = K >> 6;

    const u8* gp[3];
    u8* ld0[3];
#pragma unroll
    for (int r = 0; r < 3; ++r) {
        const int i = w * 3 + r;
        if (i < 4) {
            ld0[r] = As + (i >> 1) * 2048 + (i & 1) * 1024;
            gp[r] = al.addr(bn, bm + (i & 1) * 32 + lrow, (i >> 1) * 32 + lcolb);
        } else {
            const int jj = i - 4;
            ld0[r] = Ws + (jj >> 2) * 4096 + (jj & 3) * 1024;
            gp[r] = wl.addr(bm, bn + (jj & 3) * 32 + lrow, (jj >> 2) * 32 + lcolb);
        }
    }

    // buf: 0,1,2 rotating; A stride 4096, W stride 8192 per buf
    auto STAGE = [&](int k0, int buf) {
        const bool relA = al.reloadAt(k0);
        const bool relW = wl.reloadAt(k0);
#pragma unroll
        for (int r = 0; r < 3; ++r) {
            const int i = w * 3 + r;
            if (i < 4) {
                if (relA) gp[r] = al.addr(bn, bm + (i & 1) * 32 + lrow, k0 + (i >> 1) * 32 + lcolb);
                gl_lds16(gp[r], ld0[r] + buf * 4096);
            } else {
                const int jj = i - 4;
                if (relW) gp[r] = wl.addr(bm, bn + (jj & 3) * 32 + lrow, k0 + (jj >> 2) * 32 + lcolb);
                gl_lds16(gp[r], ld0[r] + buf * 8192);
            }
            gp[r] += 64;
        }
    };

    f32x4 acc[2][4];
#pragma unroll
    for (int m = 0; m < 2; ++m)
#pragma unroll
        for (int n = 0; n < 4; ++n) acc[m][n] = (f32x4)0.0f;

    STAGE(0, 0);
    if (nt > 1) STAGE(64, 1);

    const int frow = lane & 15, fkb = (lane >> 4) * 8;
    const int aoff = (wr * 32 + frow) * 32 + fkb;
    const int woff = (wc * 64 + frow) * 32 + fkb;

    int cbuf = 0, sbuf = 2;
    for (int t = 0; t < nt; ++t) {
        // own-wave counted wait: tile t's 3 loads done; tile t+1's stay in flight.
        if (t + 1 < nt) asm volatile("s_waitcnt vmcnt(3)" ::: "memory");
        else            asm volatile("s_waitcnt vmcnt(0)" ::: "memory");
        __builtin_amdgcn_s_barrier();   // block-wide: tile t ready everywhere
        asm volatile("" ::: "memory");

        if (t + 2 < nt) STAGE((t + 2) << 6, sbuf);   // overwrites tile t-1's buf (safe)

        const u8* ab = As + cbuf * 4096;
        const u8* wb = Ws + cbuf * 8192;
#pragma unroll
        for (int ch = 0; ch < 2; ++ch) {
            i64 af[2], bw[4];
#pragma unroll
            for (int m = 0; m < 2; ++m) af[m] = *(const i64*)(ab + ch * 2048 + aoff + m * 512);
#pragma unroll
            for (int n = 0; n < 4; ++n) bw[n] = *(const i64*)(wb + ch * 4096 + woff + n * 512);
#pragma unroll
            for (int m = 0; m < 2; ++m)
#pragma unroll
                for (int n = 0; n < 4; ++n)
                    acc[m][n] = __builtin_amdgcn_mfma_f32_16x16x32_fp8_fp8(af[m], bw[n], acc[m][n], 0, 0, 0);
        }
        cbuf = (cbuf == 2) ? 0 : cbuf + 1;
        sbuf = (sbuf == 2) ? 0 : sbuf + 1;
    }
    ep(bm, bn, wr, wc, lane, acc);
}

// ========== bf16 64x128 MFMA GEMM, BK=32 (latent-path GEMMs, unchanged) ==========
template <class ALd, class WLd, class Epi>
__global__ __launch_bounds__(256, 4) void gemm_t64(ALd al, WLd wl, Epi ep) {
    __shared__ ushort As[2 * 2048];
    __shared__ ushort Ws[2 * 4096];
    const int tid = threadIdx.x;
    const int lane = tid & 63;
    const int w = tid >> 6;
    const int wr = w >> 1, wc = w & 1;
    const int bn = blockIdx.x * 128 + al.bn0;
    const int bm = blockIdx.y * 64;
    const int grow = lane >> 2;
    const int gcol = (lane & 3) * 8;
    const int K = al.kdim(bn);
    const int nt = K >> 5;

    const ushort* gp[3];
    ushort* ld0[3];
    int lstride[3];
    bool isA[3];
#pragma unroll
    for (int r = 0; r < 3; ++r) {
        const int i = w * 3 + r;
        isA[r] = (i < 4);
        ld0[r] = isA[r] ? (As + i * 512) : (Ws + (i - 4) * 512);
        lstride[r] = isA[r] ? 2048 : 4096;
        gp[r] = isA[r] ? al.addr(bn, bm + i * 16 + grow, gcol)
                       : wl.addr(bm, bn + (i - 4) * 16 + grow, gcol);
    }

    auto STAGE = [&](int k0, int buf) {
#pragma unroll
        for (int r = 0; r < 3; ++r) {
            if (isA[r]) {
                if (al.reloadAt(k0))
                    gp[r] = al.addr(bn, bm + (w * 3 + r) * 16 + grow, k0 + gcol);
            } else {
                if (wl.reloadAt(k0))
                    gp[r] = wl.addr(bm, bn + (w * 3 + r - 4) * 16 + grow, k0 + gcol);
            }
            gl_lds16(gp[r], ld0[r] + (buf ? lstride[r] : 0));
            gp[r] += 32;
        }
    };

    f32x4 acc[2][4];
#pragma unroll
    for (int m = 0; m < 2; ++m)
#pragma unroll
        for (int n = 0; n < 4; ++n) acc[m][n] = (f32x4)0.0f;

    STAGE(0, 0);
    __syncthreads();

    const int frow = lane & 15, fk = (lane >> 4) * 8;
    const int foff = (wr * 32 + frow) * 32 + fk;
    const int goff = (wc * 64 + frow) * 32 + fk;

    for (int t = 0; t < nt; ++t) {
        if (t + 1 < nt) STAGE((t + 1) * 32, (t + 1) & 1);
        const ushort* asp = As + (t & 1) * 2048 + foff;
        const ushort* bsp = Ws + (t & 1) * 4096 + goff;
        bf16x8 af[2], bw[4];
#pragma unroll
        for (int m = 0; m < 2; ++m) af[m] = *(const bf16x8*)(asp + m * 512);
#pragma unroll
        for (int n = 0; n < 4; ++n) bw[n] = *(const bf16x8*)(bsp + n * 512);
#pragma unroll
        for (int m = 0; m < 2; ++m)
#pragma unroll
            for (int n = 0; n < 4; ++n)
                acc[m][n] = __builtin_amdgcn_mfma_f32_16x16x32_bf16(af[m], bw[n], acc[m][n], 0, 0, 0);
        __syncthreads();
    }
    ep(bm, bn, wr, wc, lane, acc);
}

// ================= fp8 loaders =================
struct ALdEnc8 {
    const u8* xe; const u8* h; int bn0;
    __device__ int kdim(int) const { return 1152; }
    __device__ bool reloadAt(int k) const { return k == 128; }
    __device__ const u8* addr(int, int row, int k) const {
        return (k < 128) ? xe + (size_t)row * 128 + k
                         : h + (size_t)row * 1024 + (k - 128);
    }
};
struct WLdEnc8 {
    const u8* W;
    __device__ bool reloadAt(int) const { return false; }
    __device__ const u8* addr(int bm, int n, int k) const {
        return W + ((size_t)(bm >> 10) * 4096 + n) * 1152 + k;
    }
};
struct ALdDec8 {
    const u8* xd; const u8* h; const u8* z; const u8* h1p; int bn0;
    __device__ int kdim(int bn) const {
        return bn < 4096 ? 1152 : (bn < 5120 ? 1280 : 1024);
    }
    __device__ bool reloadAt(int k) const { return k == 128 || k == 1152; }
    __device__ const u8* addr(int bn, int row, int k) const {
        if (bn >= 5120) return h1p + (size_t)row * 1024 + k;
        if (k < 128) return xd + (size_t)row * 128 + k;
        if (k < 1152) return h + (size_t)row * 1024 + (k - 128);
        return z + (size_t)row * 128 + (k - 1152);
    }
};
struct WLdDec8 {
    const u8* Wg4; const u8* W1; const u8* W2p;
    __device__ bool reloadAt(int) const { return false; }
    __device__ const u8* addr(int, int n, int k) const {
        if (n < 4096) return Wg4 + (size_t)n * 1152 + k;
        if (n < 5120) return W1 + (size_t)(n - 4096) * 1280 + k;
        return W2p + (size_t)(n - 5120) * 1024 + k;
    }
};

// ================= bf16 loaders (latent path) =================
struct ALdPlain {
    const ushort* A; int ld; int K; int bn0;
    __device__ int kdim(int) const { return K; }
    __device__ bool reloadAt(int) const { return false; }
    __device__ const ushort* addr(int, int row, int k) const { return A + (size_t)row * ld + k; }
};
struct WLdPlain {
    const ushort* W; int ld;
    __device__ bool reloadAt(int) const { return false; }
    __device__ const ushort* addr(int, int n, int k) const { return W + (size_t)n * ld + k; }
};

// ================= epilogues =================
struct EpiEnc8 {
    const float* b_f; const float* b_b; const int* len; int t;
    ushort* c; const u8* hc8; u8* hn8; ushort* hidp;
    __device__ void operator()(int bm, int bn, int wr, int wc, int lane,
                               f32x4 (&acc)[2][4]) const {
        const int j = ((bn >> 6) + wc) * 16 + (lane & 15);
        const int rbase = bm + wr * 32 + ((lane >> 4) << 2);
#pragma unroll
        for (int m = 0; m < 2; ++m) {
#pragma unroll
            for (int r = 0; r < 4; ++r) {
                const int row = rbase + m * 16 + r;
                const int b = row & 1023;
                const int dir = row >> 10;
                const float* bias = dir ? b_b : b_f;
                const size_t o = (size_t)row * 1024 + j;
                if (t < len[b]) {
                    float gi = acc[m][0][r] + bias[j];
                    float gf = acc[m][1][r] + bias[1024 + j];
                    float gg = acc[m][2][r] + bias[2048 + j];
                    float go = acc[m][3][r] + bias[3072 + j];
                    float nc = sigf(gf) * bf2f(c[o]) + sigf(gi) * tanhfast(gg);
                    c[o] = f2bf(nc);
                    float nh = sigf(go) * tanhfast(nc);
                    hn8[o] = f2e4(nh);
                    hidp[(size_t)b * 2048 + dir * 1024 + j] = f2bf(nh);
                } else {
                    hn8[o] = hc8[o];
                }
            }
        }
    }
};

struct EpiDec8 {
    const float *bi, *bo, *bfv, *bg, *b1, *b2;
    ushort* c; u8* hn8; u8* hid1cur;
    const int* tokens; const int* len; int t;
    float* accs;
    __device__ void operator()(int bm, int bn, int wr, int wc, int lane,
                               f32x4 (&acc)[2][4]) const {
        const int rbase = bm + wr * 32 + ((lane >> 4) << 2);
        if (bn < 4096) {
            const int j = ((bn >> 6) + wc) * 16 + (lane & 15);
#pragma unroll
            for (int m = 0; m < 2; ++m) {
#pragma unroll
                for (int r = 0; r < 4; ++r) {
                    const int b = rbase + m * 16 + r;
                    const size_t o = (size_t)b * 1024 + j;
                    float gi = sigf(acc[m][0][r] + bi[j]);
                    float go = sigf(acc[m][1][r] + bo[j]);
                    float gf = sigf(acc[m][2][r] + bfv[j]);
                    float gg = tanhfast(acc[m][3][r] + bg[j]);
                    float nc = gf * bf2f(c[o]) + gi * gg;
                    c[o] = f2bf(nc);
                    hn8[o] = f2e4(go * tanhfast(nc));
                }
            }
        } else if (bn < 5120) {
            const int cb = (bn - 4096) + wc * 64;
#pragma unroll
            for (int m = 0; m < 2; ++m)
#pragma unroll
                for (int n = 0; n < 4; ++n) {
                    const int col = cb + n * 16 + (lane & 15);
#pragma unroll
                    for (int r = 0; r < 4; ++r)
                        hid1cur[(size_t)(rbase + m * 16 + r) * 1024 + col] =
                            f2e4(fmaxf(acc[m][n][r] + b1[col], 0.0f));
                }
        } else {
            if (wc != 0) return;
            const int ts = t - 1;
            const int col0 = lane & 15;
            const bool v1ok = col0 < (V_ - 16);
            const float b2v0 = b2[col0];
            const float b2v1 = v1ok ? b2[16 + col0] : 0.0f;
            float ce_loc = 0.f, cor_loc = 0.f, msk_loc = 0.f;
#pragma unroll
            for (int m = 0; m < 2; ++m) {
#pragma unroll
                for (int r = 0; r < 4; ++r) {
                    const int b = rbase + m * 16 + r;
                    const int lb = len[b];
                    float v0 = acc[m][0][r] + b2v0;
                    float v1 = v1ok ? (acc[m][1][r] + b2v1) : -1e30f;
                    float mv; int mi;
                    if (v1 > v0) { mv = v1; mi = 16 + col0; } else { mv = v0; mi = col0; }
#pragma unroll
                    for (int s = 1; s < 16; s <<= 1) {
                        float ov = __shfl_xor(mv, s);
                        int oi = __shfl_xor(mi, s);
                        if (ov > mv || (ov == mv && oi < mi)) { mv = ov; mi = oi; }
                    }
                    float se = expf(v0 - mv) + (v1ok ? expf(v1 - mv) : 0.0f);
#pragma unroll
                    for (int s = 1; s < 16; s <<= 1) se += __shfl_xor(se, s);
                    float lse = mv + logf(se);
                    int tgt = (ts < lb) ? tokens[b * T_ + ts] : 0;
                    int srcl = (lane & 48) | (tgt & 15);
                    float sv0 = __shfl(v0, srcl);
                    float sv1 = __shfl(v1, srcl);
                    float stgt = (tgt < 16) ? sv0 : sv1;
                    if (ts <= lb && col0 == 0) {
                        ce_loc += lse - stgt;
                        cor_loc += (mi == tgt) ? 1.0f : 0.0f;
                        msk_loc += 1.0f;
                    }
                }
            }
            float ce = __shfl(ce_loc, 0) + __shfl(ce_loc, 16) + __shfl(ce_loc, 32) + __shfl(ce_loc, 48);
            float co = __shfl(cor_loc, 0) + __shfl(cor_loc, 16) + __shfl(cor_loc, 32) + __shfl(cor_loc, 48);
            float mk = __shfl(msk_loc, 0) + __shfl(msk_loc, 16) + __shfl(msk_loc, 32) + __shfl(msk_loc, 48);
            if (lane == 0) {
                atomicAdd(&accs[0], ce);
                atomicAdd(&accs[1], co);
                atomicAdd(&accs[2], mk);
            }
        }
    }
};

struct EpiStoreF32 {
    float* out; int ldc;
    __device__ void operator()(int bm, int bn, int wr, int wc, int lane,
                               f32x4 (&acc)[2][4]) const {
        const int rbase = bm + wr * 32 + ((lane >> 4) << 2);
        const int cbase = bn + wc * 64 + (lane & 15);
#pragma unroll
        for (int m = 0; m < 2; ++m)
#pragma unroll
            for (int n = 0; n < 4; ++n)
#pragma unroll
                for (int r = 0; r < 4; ++r)
                    out[(size_t)(rbase + m * 16 + r) * ldc + cbase + n * 16] = acc[m][n][r];
    }
};
struct EpiBiasF8 {
    u8* out; const float* bias;
    __device__ void operator()(int bm, int bn, int wr, int wc, int lane,
                               f32x4 (&acc)[2][4]) const {
        const int rbase = bm + wr * 32 + ((lane >> 4) << 2);
        const int cbase = bn + wc * 64 + (lane & 15);
#pragma unroll
        for (int m = 0; m < 2; ++m)
#pragma unroll
            for (int n = 0; n < 4; ++n) {
                const int col = cbase + n * 16;
#pragma unroll
                for (int r = 0; r < 4; ++r)
                    out[(size_t)(rbase + m * 16 + r) * 1024 + col] = f2e4(acc[m][n][r] + bias[col]);
            }
    }
};

// ================= packing / elementwise =================
__global__ void pack_cols(const float* __restrict__ src, int src_ld,
                          ushort* __restrict__ dst, int dst_ld, int dcol0,
                          int rows, int cols) {
    int i = blockIdx.x * 256 + threadIdx.x;
    int c4cnt = cols >> 2;
    if (i >= rows * c4cnt) return;
    int r = i / c4cnt, c4 = (i - r * c4cnt) * 4;
    float4 v = *(const float4*)(src + (size_t)r * src_ld + c4);
    ushort4 o = { f2bf(v.x), f2bf(v.y), f2bf(v.z), f2bf(v.w) };
    *(ushort4*)(dst + (size_t)r * dst_ld + dcol0 + c4) = o;
}

__global__ void pack_cols8(const float* __restrict__ src, int src_ld,
                           u8* __restrict__ dst, int dst_ld, int rows, int cols) {
    int i = blockIdx.x * 256 + threadIdx.x;
    int c4cnt = cols >> 2;
    if (i >= rows * c4cnt) return;
    int r = i / c4cnt, c4 = (i - r * c4cnt) * 4;
    float4 v = *(const float4*)(src + (size_t)r * src_ld + c4);
    unsigned o = f2e4(v.x) | ((unsigned)f2e4(v.y) << 8) |
                 ((unsigned)f2e4(v.z) << 16) | ((unsigned)f2e4(v.w) << 24);
    *(unsigned*)(dst + (size_t)r * dst_ld + c4) = o;
}

__global__ void pack_gates_enc8(const float* __restrict__ Wih_f, const float* __restrict__ Whh_f,
                                const float* __restrict__ Wih_b, const float* __restrict__ Whh_b,
                                u8* __restrict__ dst) {
    int i = blockIdx.x * 256 + threadIdx.x;
    if (i >= 2 * 4096 * 288) return;
    int c4 = (i % 288) * 4;
    int p = (i / 288) & 4095;
    int dir = i / (288 * 4096);
    int j = ((p >> 6) << 4) + (p & 15);
    int g = (p >> 4) & 3;
    int srow = g * 1024 + j;
    float4 v;
    if (c4 < 128) {
        const float* s = dir ? Wih_b : Wih_f;
        v = *(const float4*)(s + (size_t)srow * 128 + c4);
    } else {
        const float* s = dir ? Whh_b : Whh_f;
        v = *(const float4*)(s + (size_t)srow * 1024 + (c4 - 128));
    }
    unsigned o = f2e4(v.x) | ((unsigned)f2e4(v.y) << 8) |
                 ((unsigned)f2e4(v.z) << 16) | ((unsigned)f2e4(v.w) << 24);
    *(unsigned*)(dst + ((size_t)dir * 4096 + p) * 1152 + c4) = o;
}

__global__ void pack_gates_dec8(const float* __restrict__ Wi, const float* __restrict__ Wo,
                                const float* __restrict__ Wf, const float* __restrict__ Wg,
                                u8* __restrict__ dst) {
    int i = blockIdx.x * 256 + threadIdx.x;
    if (i >= 4096 * 288) return;
    int c4 = (i % 288) * 4;
    int p = i / 288;
    int j = ((p >> 6) << 4) + (p & 15);
    int g = (p >> 4) & 3;
    const float* s = (g == 0) ? Wi : (g == 1) ? Wo : (g == 2) ? Wf : Wg;
    float4 v = *(const float4*)(s + (size_t)j * 1152 + c4);
    unsigned o = f2e4(v.x) | ((unsigned)f2e4(v.y) << 8) |
                 ((unsigned)f2e4(v.z) << 16) | ((unsigned)f2e4(v.w) << 24);
    *(unsigned*)(dst + (size_t)p * 1152 + c4) = o;
}

__global__ void pack_w28(const float* __restrict__ W2, u8* __restrict__ dst) {
    int i = blockIdx.x * 256 + threadIdx.x;
    if (i >= 128 * 256) return;
    int r = i >> 8, c4 = (i & 255) * 4;
    unsigned o = 0;
    if (r < V_) {
        float4 v = *(const float4*)(W2 + (size_t)r * 1024 + c4);
        o = f2e4(v.x) | ((unsigned)f2e4(v.y) << 8) |
            ((unsigned)f2e4(v.z) << 16) | ((unsigned)f2e4(v.w) << 24);
    }
    *(unsigned*)(dst + (size_t)r * 1024 + c4) = o;
}

__global__ void pack_xenc8(const float* __restrict__ xenc, const int* __restrict__ len,
                           u8* __restrict__ xe) {
    int i = blockIdx.x * 256 + threadIdx.x;
    if (i >= 15 * 2048 * 32) return;
    int c4 = (i & 31) * 4;
    int r = (i >> 5) & 2047;
    int t = i >> 16;
    int dir = r >> 10, b = r & 1023;
    int tt = t;
    if (dir) {
        int ri = len[b] - 1 - t;
        tt = ri < 0 ? 0 : (ri > T_ - 1 ? T_ - 1 : ri);
    }
    float4 v = *(const float4*)(xenc + ((size_t)b * T_ + tt) * 128 + c4);
    unsigned o = f2e4(v.x) | ((unsigned)f2e4(v.y) << 8) |
                 ((unsigned)f2e4(v.z) << 16) | ((unsigned)f2e4(v.w) << 24);
    *(unsigned*)(xe + ((size_t)t * 2048 + r) * 128 + c4) = o;
}

__global__ void pack_xdec8(const float* __restrict__ emb, const int* __restrict__ tokens,
                           u8* __restrict__ xd) {
    int i = blockIdx.x * 256 + threadIdx.x;
    if (i >= 15 * 1024 * 32) return;
    int c4 = (i & 31) * 4;
    int b = (i >> 5) & 1023;
    int t = i >> 15;
    unsigned o = 0;
    if (t > 0) {
        int tok = tokens[(size_t)b * T_ + (t - 1)];
        float4 v = *(const float4*)(emb + (size_t)tok * 128 + c4);
        o = f2e4(v.x) | ((unsigned)f2e4(v.y) << 8) |
            ((unsigned)f2e4(v.z) << 16) | ((unsigned)f2e4(v.w) << 24);
    }
    *(unsigned*)(xd + ((size_t)t * 1024 + b) * 128 + c4) = o;
}

__global__ void init_zero(ushort* cenc, ushort* cdec, u8* h8A, float* accs) {
    int i = blockIdx.x * 256 + threadIdx.x;
    if (i < 2 * 1024 * 1024) { cenc[i] = 0; h8A[i] = 0; }
    if (i < 1024 * 1024) cdec[i] = 0;
    if (i < 8) accs[i] = 0.0f;
}

__global__ void latent_ew(const float* __restrict__ ml, const float* __restrict__ bmv,
                          const float* __restrict__ blv, const float* __restrict__ eps,
                          ushort* __restrict__ zb, u8* __restrict__ z8,
                          float* __restrict__ klacc) {
    int idx = blockIdx.x * 256 + threadIdx.x;
    int b = idx >> 7, l = idx & (L_ - 1);
    float mean = ml[(size_t)b * 256 + l] + bmv[l];
    float logv = ml[(size_t)b * 256 + L_ + l] + blv[l];
    float zv = eps[idx] * expf(0.5f * logv) + mean;
    zb[idx] = f2bf(zv);
    z8[idx] = f2e4(zv);
    float part = 1.0f + logv - mean * mean - expf(logv);
    for (int off = 32; off; off >>= 1) part += __shfl_down(part, off);
    __shared__ float s[4];
    int lane = threadIdx.x & 63, wv = threadIdx.x >> 6;
    if (lane == 0) s[wv] = part;
    __syncthreads();
    if (threadIdx.x == 0) atomicAdd(klacc, s[0] + s[1] + s[2] + s[3]);
}

__global__ void finalize_k(const float* accs, float* out) {
    if (threadIdx.x == 0 && blockIdx.x == 0) {
        float kl = -0.5f * accs[3] / (float)B_;
        float amino = accs[0] / (float)B_;
        out[0] = amino + 0.1f * kl;
        out[1] = amino;
        out[2] = kl;
        out[3] = accs[1] / accs[2];
    }
}

// ================= host =================
extern "C" void kernel_launch(void* const* d_in, const int* in_sizes, int n_in,
                              void* d_out, int out_size, void* d_ws, size_t ws_size,
                              hipStream_t stream) {
    (void)in_sizes; (void)n_in; (void)out_size; (void)ws_size;
    const float* x_enc  = (const float*)d_in[0];
    const int*   tokens = (const int*)d_in[1];
    const int*   lengths= (const int*)d_in[2];
    const float* eps    = (const float*)d_in[3];
    const float* emb    = (const float*)d_in[4];
    const float* Wih_f  = (const float*)d_in[5];
    const float* Whh_f  = (const float*)d_in[6];
    const float* b_f    = (const float*)d_in[7];
    const float* Wih_b  = (const float*)d_in[8];
    const float* Whh_b  = (const float*)d_in[9];
    const float* b_b    = (const float*)d_in[10];
    const float* Wm     = (const float*)d_in[11];
    const float* bm     = (const float*)d_in[12];
    const float* Wl     = (const float*)d_in[13];
    const float* bl     = (const float*)d_in[14];
    const float* Wz     = (const float*)d_in[15];
    const float* bz     = (const float*)d_in[16];
    const float* Wi     = (const float*)d_in[17];
    const float* bi     = (const float*)d_in[18];
    const float* Wo     = (const float*)d_in[19];
    const float* bo     = (const float*)d_in[20];
    const float* Wfm    = (const float*)d_in[21];
    const float* bf     = (const float*)d_in[22];
    const float* Wg     = (const float*)d_in[23];
    const float* bg     = (const float*)d_in[24];
    const float* W1     = (const float*)d_in[25];
    const float* b1     = (const float*)d_in[26];
    const float* W2     = (const float*)d_in[27];
    const float* b2     = (const float*)d_in[28];

    float*  ml   = (float*)d_ws;
    float*  accs = ml + 262144;
    ushort* cenc = (ushort*)(accs + 64);
    ushort* cdec = cenc + 2 * 1024 * 1024;
    ushort* hidp = cdec + 1024 * 1024;
    ushort* Wml  = hidp + 2 * 1024 * 1024;
    ushort* Wzp  = Wml + 256 * 2048;
    ushort* zb   = Wzp + 1024 * 128;
    u8* h8A  = (u8*)(zb + 1024 * 128);
    u8* h8B  = h8A + 2 * 1024 * 1024;
    u8* hd8A = h8B + 2 * 1024 * 1024;
    u8* hd8B = hd8A + 1024 * 1024;
    u8* h18A = hd8B + 1024 * 1024;
    u8* h18B = h18A + 1024 * 1024;
    u8* z8   = h18B + 1024 * 1024;
    u8* xe8  = z8 + 1024 * 128;
    u8* xd8  = xe8 + 15 * 2048 * 128;
    u8* Wenc8= xd8 + 15 * 1024 * 128;
    u8* Wdec8= Wenc8 + 2 * 4096 * 1152;
    u8* W1p8 = Wdec8 + 4096 * 1152;
    u8* W2p8 = W1p8 + 1024 * 1280;

    init_zero<<<8192, 256, 0, stream>>>(cenc, cdec, h8A, accs);
    pack_gates_enc8<<<9216, 256, 0, stream>>>(Wih_f, Whh_f, Wih_b, Whh_b, Wenc8);
    pack_gates_dec8<<<4608, 256, 0, stream>>>(Wi, Wo, Wfm, Wg, Wdec8);
    pack_cols8<<<1280, 256, 0, stream>>>(W1, 1280, W1p8, 1280, 1024, 1280);
    pack_cols<<<256, 256, 0, stream>>>(Wm, 2048, Wml, 2048, 0, L_, 2048);
    pack_cols<<<256, 256, 0, stream>>>(Wl, 2048, Wml + L_ * 2048, 2048, 0, L_, 2048);
    pack_cols<<<128, 256, 0, stream>>>(Wz, L_, Wzp, L_, 0, H_, L_);
    pack_w28<<<128, 256, 0, stream>>>(W2, W2p8);
    pack_xenc8<<<3840, 256, 0, stream>>>(x_enc, lengths, xe8);
    pack_xdec8<<<1920, 256, 0, stream>>>(emb, tokens, xd8);

    // ---- encoder: fp8 ring-3, grid (32, 32) = 1024 blocks = 4/CU ----
    {
        const u8* hc = h8A; u8* hn = h8B;
        for (int t = 0; t < T_; ++t) {
            gemm_f8<<<dim3(32, 32), 256, 0, stream>>>(
                ALdEnc8{ xe8 + (size_t)t * 2048 * 128, hc, 0 }, WLdEnc8{ Wenc8 },
                EpiEnc8{ b_f, b_b, lengths, t, cenc, hc, hn, hidp });
            const u8* tmp = hn; hn = (u8*)hc; hc = tmp;
        }
    }
    // ---- latents (bf16 path) ----
    gemm_t64<<<dim3(2, 16), 256, 0, stream>>>(
        ALdPlain{ hidp, 2048, 2048, 0 }, WLdPlain{ Wml, 2048 }, EpiStoreF32{ ml, 256 });
    latent_ew<<<512, 256, 0, stream>>>(ml, bm, bl, eps, zb, z8, &accs[3]);
    gemm_t64<<<dim3(8, 16), 256, 0, stream>>>(
        ALdPlain{ zb, 128, 128, 0 }, WLdPlain{ Wzp, 128 }, EpiBiasF8{ hd8A, bz });

    // ---- decoder: fp8 ring-3, scores(t-1) fused ----
    {
        const u8* dc = hd8A; u8* dn = hd8B;
        for (int t = 0; t < T_; ++t) {
            u8* h1c = (t & 1) ? h18B : h18A;
            const u8* h1p = (t & 1) ? h18A : h18B;
            dim3 grid(t == 0 ? 40 : 41, 16);
            gemm_f8<<<grid, 256, 0, stream>>>(
                ALdDec8{ xd8 + (size_t)t * 1024 * 128, dc, z8, h1p, 0 },
                WLdDec8{ Wdec8, W1p8, W2p8 },
                EpiDec8{ bi, bo, bf, bg, b1, b2, cdec, dn, h1c, tokens, lengths, t, accs });
            const u8* tmp = dn; dn = (u8*)dc; dc = tmp;
        }
        gemm_f8<<<dim3(1, 16), 256, 0, stream>>>(
            ALdDec8{ xd8, dc, z8, h18A, 5120 },
            WLdDec8{ Wdec8, W1p8, W2p8 },
            EpiDec8{ bi, bo, bf, bg, b1, b2, cdec, hd8B, h18B, tokens, lengths, T_, accs });
    }

    finalize_k<<<1, 64, 0, stream>>>(accs, (float*)d_out);
}

// Round 12
// 865.912 us; speedup vs baseline: 1.2991x; 1.2991x over previous
//
#include <hip/hip_runtime.h>
#include <math.h>

#define B_ 1024
#define T_ 15
#define E_ 128
#define H_ 1024
#define L_ 128
#define V_ 21

typedef unsigned char u8;
typedef long i64;
typedef __attribute__((ext_vector_type(2))) long i64x2;
typedef __attribute__((ext_vector_type(8))) short bf16x8;
typedef __attribute__((ext_vector_type(4))) float f32x4;

__device__ __forceinline__ float sigf(float x) { return 1.0f / (1.0f + __expf(-x)); }
__device__ __forceinline__ float tanhfast(float x) {
    float t = __expf(-2.0f * fabsf(x));
    float r = (1.0f - t) / (1.0f + t);
    return copysignf(r, x);
}

__device__ __forceinline__ ushort f2bf(float f) {
    unsigned u = __float_as_uint(f);
    u += 0x7fffu + ((u >> 16) & 1u);
    return (ushort)(u >> 16);
}
__device__ __forceinline__ float bf2f(ushort u) {
    return __uint_as_float((unsigned)u << 16);
}

// f32 -> OCP e4m3fn, RNE, saturate to 448
__device__ __forceinline__ u8 f2e4(float x) {
    unsigned u = __float_as_uint(x);
    u8 s = (u >> 24) & 0x80;
    float ax = fminf(fabsf(x), 448.0f);
    unsigned ua = __float_as_uint(ax);
    int e = (int)(ua >> 23) - 127;
    if (e < -6) {
        int q = (int)rintf(ax * 512.0f);
        return s | (u8)q;
    }
    unsigned m = ua & 0x7FFFFFu;
    unsigned lsb = (m >> 20) & 1u;
    m += 0x7FFFFu + lsb;
    if (m >> 23) { m = 0; e += 1; }
    if (e > 8) return s | 0x7E;
    return s | (u8)(((e + 7) << 3) | (m >> 20));
}

// Fragment layout (fp8 16x16x32 MFMA, K-tile=64 = 2 ch of 32):
// unit = 1024 B covering 16 rows x 64 k: lane l holds row (l&15),
// k-bytes: ch0 [q*8..q*8+8) and ch1 [32+q*8..) with q = l>>4, packed as
// lane's 16 B = [ch0 8B][ch1 8B]. Byte offset of (row,k') in a unit:
//   ch=k'>>5, q=(k'>>3)&3, bb=k'&7 -> ((q<<4)|(row&15))*16 + ch*8 + bb
__device__ __forceinline__ size_t frag_off(int row, int kp) {
    int ch = kp >> 5, q = (kp >> 3) & 3, bb = kp & 7;
    return (size_t)(((q << 4) | (row & 15)) * 16 + ch * 8 + bb);
}

// ========== fp8 64x128 MFMA GEMM, register-direct (no LDS, no barriers) =========
// A frag-packed: per k-tile, RG rowgroups of 1024B units. W frag-packed: per
// block: nt tiles x 8 units (wc*4+n). Each wave loads its 2 A-units + 4 W-units
// per tile (global_load_dwordx4, coalesced 1KB/instr), 2-tile register
// ping-pong (named sets, rule #20). Waves run free; TLP + 1-tile prefetch
// hides L2 latency.
template <class ALd, class WLd, class Epi>
__global__ __launch_bounds__(256, 4) void gemm_reg(ALd al, WLd wl, Epi ep) {
    const int tid = threadIdx.x;
    const int lane = tid & 63;
    const int w = tid >> 6;
    const int wr = w >> 1, wc = w & 1;
    const int bn = blockIdx.x * 128 + al.bn0;
    const int bm = blockIdx.y * 64;
    const int nt = al.ntiles(bn);
    const int lb = lane * 16;
    const int rg0 = (bm >> 4) + wr * 2;

    const u8* wbase = wl.base(bm, bn) + (size_t)(wc * 4) * 1024 + lb;

    f32x4 acc[2][4];
#pragma unroll
    for (int m = 0; m < 2; ++m)
#pragma unroll
        for (int n = 0; n < 4; ++n) acc[m][n] = (f32x4)0.0f;

    i64x2 a0[2], a1[2], w0[4], w1[4];

    auto LOADA = [&](int t, i64x2* dst) {
        const u8* tb = al.tile(bn, t) + lb;
        dst[0] = *(const i64x2*)(tb + (size_t)rg0 * 1024);
        dst[1] = *(const i64x2*)(tb + (size_t)(rg0 + 1) * 1024);
    };
    auto LOADW = [&](int t, i64x2* dst) {
        const u8* tb = wbase + (size_t)t * 8192;
#pragma unroll
        for (int n = 0; n < 4; ++n) dst[n] = *(const i64x2*)(tb + n * 1024);
    };
    auto STEP = [&](i64x2* a, i64x2* wv) {
#pragma unroll
        for (int m = 0; m < 2; ++m)
#pragma unroll
            for (int n = 0; n < 4; ++n)
                acc[m][n] = __builtin_amdgcn_mfma_f32_16x16x32_fp8_fp8(a[m].x, wv[n].x, acc[m][n], 0, 0, 0);
#pragma unroll
        for (int m = 0; m < 2; ++m)
#pragma unroll
            for (int n = 0; n < 4; ++n)
                acc[m][n] = __builtin_amdgcn_mfma_f32_16x16x32_fp8_fp8(a[m].y, wv[n].y, acc[m][n], 0, 0, 0);
    };

    LOADA(0, a0); LOADW(0, w0);
    for (int t = 0; t < nt; t += 2) {          // nt always even (18/20/16)
        LOADA(t + 1, a1); LOADW(t + 1, w1);
        STEP(a0, w0);
        if (t + 2 < nt) { LOADA(t + 2, a0); LOADW(t + 2, w0); }
        STEP(a1, w1);
    }
    ep(bm, bn, wr, wc, lane, acc);
}

// ========== bf16 64x128 MFMA GEMM, BK=32 LDS (latent-path GEMMs only) ==========
template <class ALd, class WLd, class Epi>
__global__ __launch_bounds__(256, 4) void gemm_t64(ALd al, WLd wl, Epi ep) {
    __shared__ ushort As[2 * 2048];
    __shared__ ushort Ws[2 * 4096];
    const int tid = threadIdx.x;
    const int lane = tid & 63;
    const int w = tid >> 6;
    const int wr = w >> 1, wc = w & 1;
    const int bn = blockIdx.x * 128;
    const int bm = blockIdx.y * 64;
    const int grow = lane >> 2;
    const int gcol = (lane & 3) * 8;
    const int K = al.K;
    const int nt = K >> 5;

    const ushort* gp[3];
    ushort* ld0[3];
    int lstride[3];
    bool isA[3];
#pragma unroll
    for (int r = 0; r < 3; ++r) {
        const int i = w * 3 + r;
        isA[r] = (i < 4);
        ld0[r] = isA[r] ? (As + i * 512) : (Ws + (i - 4) * 512);
        lstride[r] = isA[r] ? 2048 : 4096;
        gp[r] = isA[r] ? al.addr(bm + i * 16 + grow, gcol)
                       : wl.addr(bn + (i - 4) * 16 + grow, gcol);
    }

    auto STAGE = [&](int buf) {
#pragma unroll
        for (int r = 0; r < 3; ++r) {
            __builtin_amdgcn_global_load_lds(
                (const __attribute__((address_space(1))) void*)gp[r],
                (__attribute__((address_space(3))) void*)(ld0[r] + (buf ? lstride[r] : 0)), 16, 0, 0);
            gp[r] += 32;
        }
    };

    f32x4 acc[2][4];
#pragma unroll
    for (int m = 0; m < 2; ++m)
#pragma unroll
        for (int n = 0; n < 4; ++n) acc[m][n] = (f32x4)0.0f;

    STAGE(0);
    __syncthreads();

    const int frow = lane & 15, fk = (lane >> 4) * 8;
    const int foff = (wr * 32 + frow) * 32 + fk;
    const int goff = (wc * 64 + frow) * 32 + fk;

    for (int t = 0; t < nt; ++t) {
        if (t + 1 < nt) STAGE((t + 1) & 1);
        const ushort* asp = As + (t & 1) * 2048 + foff;
        const ushort* bsp = Ws + (t & 1) * 4096 + goff;
        bf16x8 af[2], bw[4];
#pragma unroll
        for (int m = 0; m < 2; ++m) af[m] = *(const bf16x8*)(asp + m * 512);
#pragma unroll
        for (int n = 0; n < 4; ++n) bw[n] = *(const bf16x8*)(bsp + n * 512);
#pragma unroll
        for (int m = 0; m < 2; ++m)
#pragma unroll
            for (int n = 0; n < 4; ++n)
                acc[m][n] = __builtin_amdgcn_mfma_f32_16x16x32_bf16(af[m], bw[n], acc[m][n], 0, 0, 0);
        __syncthreads();
    }
    ep(bm, bn, wr, wc, lane, acc);
}

// ================= gemm_reg loaders =================
struct AEnc {  // A tiles: 0-1 xef (this step), 2-17 hf; RG=128
    const u8* xef; const u8* hf; int bn0;
    __device__ int ntiles(int) const { return 18; }
    __device__ const u8* tile(int, int t) const {
        return t < 2 ? xef + (size_t)t * 131072 : hf + (size_t)(t - 2) * 131072;
    }
};
struct WEnc {  // [2 dir][32 bnb][18 kt][8 units][1024]
    const u8* W;
    __device__ const u8* base(int bm, int bn) const {
        return W + ((size_t)(bm >> 10) * 32 + (bn >> 7)) * (18 * 8192);
    }
};
struct ADec {  // gates/W1: tiles 0-1 xdf, 2-17 hf, 18-19 z8f; scores: h1f; RG=64
    const u8* xdf; const u8* hf; const u8* z8f; const u8* h1f; int bn0;
    __device__ int ntiles(int bn) const {
        return bn < 4096 ? 18 : (bn < 5120 ? 20 : 16);
    }
    __device__ const u8* tile(int bn, int t) const {
        if (bn >= 5120) return h1f + (size_t)t * 65536;
        if (t < 2) return xdf + (size_t)t * 65536;
        if (t < 18) return hf + (size_t)(t - 2) * 65536;
        return z8f + (size_t)(t - 18) * 65536;
    }
};
struct WDec {
    const u8* Wg; const u8* W1; const u8* W2;
    __device__ const u8* base(int, int bn) const {
        if (bn < 4096) return Wg + (size_t)(bn >> 7) * (18 * 8192);
        if (bn < 5120) return W1 + (size_t)((bn - 4096) >> 7) * (20 * 8192);
        return W2;
    }
};

// ================= gemm_t64 loaders (latent path) =================
struct ALdPlain {
    const ushort* A; int ld; int K;
    __device__ const ushort* addr(int row, int k) const { return A + (size_t)row * ld + k; }
};
struct WLdPlain {
    const ushort* W; int ld;
    __device__ const ushort* addr(int n, int k) const { return W + (size_t)n * ld + k; }
};

// ================= epilogues =================
struct EpiEnc8 {  // fused encoder LSTM cell; frag n = gate n (i,f,g,o)
    const float* b_f; const float* b_b; const int* len; int t;
    ushort* c; const u8* hc8; u8* hn8; ushort* hidp;   // hc8/hn8: frag arrays [16][128][1024]
    __device__ void operator()(int bm, int bn, int wr, int wc, int lane,
                               f32x4 (&acc)[2][4]) const {
        const int j = ((bn >> 6) + wc) * 16 + (lane & 15);
        const int rbase = bm + wr * 32 + ((lane >> 4) << 2);
        // frag coords for k = j+128 (lane-constant)
        const int kt = (j + 128) >> 6;            // 2..17
        const int kp = (j + 128) & 63;
        const size_t fo = frag_off(0, kp);        // add row terms per value
#pragma unroll
        for (int m = 0; m < 2; ++m) {
#pragma unroll
            for (int r = 0; r < 4; ++r) {
                const int row = rbase + m * 16 + r;
                const int b = row & 1023;
                const int dir = row >> 10;
                const float* bias = dir ? b_b : b_f;
                const size_t off = ((size_t)(kt - 2) * 128 + (row >> 4)) * 1024 +
                                   fo + (size_t)(row & 15) * 16;
                if (t < len[b]) {
                    float gi = acc[m][0][r] + bias[j];
                    float gf = acc[m][1][r] + bias[1024 + j];
                    float gg = acc[m][2][r] + bias[2048 + j];
                    float go = acc[m][3][r] + bias[3072 + j];
                    const size_t o = (size_t)row * 1024 + j;
                    float nc = sigf(gf) * bf2f(c[o]) + sigf(gi) * tanhfast(gg);
                    c[o] = f2bf(nc);
                    float nh = sigf(go) * tanhfast(nc);
                    hn8[off] = f2e4(nh);
                    hidp[(size_t)b * 2048 + dir * 1024 + j] = f2bf(nh);
                } else {
                    hn8[off] = hc8[off];
                }
            }
        }
    }
};

struct EpiDec8 {
    const float *bi, *bo, *bfv, *bg, *b1, *b2;
    ushort* c; u8* hn8; u8* hid1cur;                  // frag arrays [16][64][1024]
    const int* tokens; const int* len; int t;
    float* accs;
    __device__ void operator()(int bm, int bn, int wr, int wc, int lane,
                               f32x4 (&acc)[2][4]) const {
        const int rbase = bm + wr * 32 + ((lane >> 4) << 2);
        if (bn < 4096) {            // fused decoder LSTM cell (i,o,f,g)
            const int j = ((bn >> 6) + wc) * 16 + (lane & 15);
            const int kt = (j + 128) >> 6;
            const int kp = (j + 128) & 63;
            const size_t fo = frag_off(0, kp);
#pragma unroll
            for (int m = 0; m < 2; ++m) {
#pragma unroll
                for (int r = 0; r < 4; ++r) {
                    const int b = rbase + m * 16 + r;
                    const size_t o = (size_t)b * 1024 + j;
                    float gi = sigf(acc[m][0][r] + bi[j]);
                    float go = sigf(acc[m][1][r] + bo[j]);
                    float gf = sigf(acc[m][2][r] + bfv[j]);
                    float gg = tanhfast(acc[m][3][r] + bg[j]);
                    float nc = gf * bf2f(c[o]) + gi * gg;
                    c[o] = f2bf(nc);
                    const size_t off = ((size_t)(kt - 2) * 64 + (b >> 4)) * 1024 +
                                       fo + (size_t)(b & 15) * 16;
                    hn8[off] = f2e4(go * tanhfast(nc));
                }
            }
        } else if (bn < 5120) {     // hid1 = relu(ah@W1^T + b1) -> frag (k=col)
            const int cb = (bn - 4096) + wc * 64;
#pragma unroll
            for (int m = 0; m < 2; ++m)
#pragma unroll
                for (int n = 0; n < 4; ++n) {
                    const int col = cb + n * 16 + (lane & 15);
                    const int kt = col >> 6;
                    const size_t fo = frag_off(0, col & 63);
#pragma unroll
                    for (int r = 0; r < 4; ++r) {
                        const int row = rbase + m * 16 + r;
                        const size_t off = ((size_t)kt * 64 + (row >> 4)) * 1024 +
                                           fo + (size_t)(row & 15) * 16;
                        hid1cur[off] = f2e4(fmaxf(acc[m][n][r] + b1[col], 0.0f));
                    }
                }
        } else {                    // scores(t-1): CE/argmax, wave-parallel
            if (wc != 0) return;
            const int ts = t - 1;
            const int col0 = lane & 15;
            const bool v1ok = col0 < (V_ - 16);
            const float b2v0 = b2[col0];
            const float b2v1 = v1ok ? b2[16 + col0] : 0.0f;
            float ce_loc = 0.f, cor_loc = 0.f, msk_loc = 0.f;
#pragma unroll
            for (int m = 0; m < 2; ++m) {
#pragma unroll
                for (int r = 0; r < 4; ++r) {
                    const int b = rbase + m * 16 + r;
                    const int lb = len[b];
                    float v0 = acc[m][0][r] + b2v0;
                    float v1 = v1ok ? (acc[m][1][r] + b2v1) : -1e30f;
                    float mv; int mi;
                    if (v1 > v0) { mv = v1; mi = 16 + col0; } else { mv = v0; mi = col0; }
#pragma unroll
                    for (int s = 1; s < 16; s <<= 1) {
                        float ov = __shfl_xor(mv, s);
                        int oi = __shfl_xor(mi, s);
                        if (ov > mv || (ov == mv && oi < mi)) { mv = ov; mi = oi; }
                    }
                    float se = expf(v0 - mv) + (v1ok ? expf(v1 - mv) : 0.0f);
#pragma unroll
                    for (int s = 1; s < 16; s <<= 1) se += __shfl_xor(se, s);
                    float lse = mv + logf(se);
                    int tgt = (ts < lb) ? tokens[b * T_ + ts] : 0;
                    int srcl = (lane & 48) | (tgt & 15);
                    float sv0 = __shfl(v0, srcl);
                    float sv1 = __shfl(v1, srcl);
                    float stgt = (tgt < 16) ? sv0 : sv1;
                    if (ts <= lb && col0 == 0) {
                        ce_loc += lse - stgt;
                        cor_loc += (mi == tgt) ? 1.0f : 0.0f;
                        msk_loc += 1.0f;
                    }
                }
            }
            float ce = __shfl(ce_loc, 0) + __shfl(ce_loc, 16) + __shfl(ce_loc, 32) + __shfl(ce_loc, 48);
            float co = __shfl(cor_loc, 0) + __shfl(cor_loc, 16) + __shfl(cor_loc, 32) + __shfl(cor_loc, 48);
            float mk = __shfl(msk_loc, 0) + __shfl(msk_loc, 16) + __shfl(msk_loc, 32) + __shfl(msk_loc, 48);
            if (lane == 0) {
                atomicAdd(&accs[0], ce);
                atomicAdd(&accs[1], co);
                atomicAdd(&accs[2], mk);
            }
        }
    }
};

struct EpiStoreF32 {
    float* out; int ldc;
    __device__ void operator()(int bm, int bn, int wr, int wc, int lane,
                               f32x4 (&acc)[2][4]) const {
        const int rbase = bm + wr * 32 + ((lane >> 4) << 2);
        const int cbase = bn + wc * 64 + (lane & 15);
#pragma unroll
        for (int m = 0; m < 2; ++m)
#pragma unroll
            for (int n = 0; n < 4; ++n)
#pragma unroll
                for (int r = 0; r < 4; ++r)
                    out[(size_t)(rbase + m * 16 + r) * ldc + cbase + n * 16] = acc[m][n][r];
    }
};
struct EpiBiasF8Frag {   // h0 = z@Wz^T + bz -> decoder hf frag (k = col+128)
    u8* out; const float* bias;
    __device__ void operator()(int bm, int bn, int wr, int wc, int lane,
                               f32x4 (&acc)[2][4]) const {
        const int rbase = bm + wr * 32 + ((lane >> 4) << 2);
        const int cbase = bn + wc * 64 + (lane & 15);
#pragma unroll
        for (int m = 0; m < 2; ++m)
#pragma unroll
            for (int n = 0; n < 4; ++n) {
                const int col = cbase + n * 16;
                const int kt = (col + 128) >> 6;
                const size_t fo = frag_off(0, col & 63);
#pragma unroll
                for (int r = 0; r < 4; ++r) {
                    const int row = rbase + m * 16 + r;
                    const size_t off = ((size_t)(kt - 2) * 64 + (row >> 4)) * 1024 +
                                       fo + (size_t)(row & 15) * 16;
                    out[off] = f2e4(acc[m][n][r] + bias[col]);
                }
            }
    }
};

// ================= packing =================
__global__ void pack_cols(const float* __restrict__ src, int src_ld,
                          ushort* __restrict__ dst, int dst_ld, int dcol0,
                          int rows, int cols) {
    int i = blockIdx.x * 256 + threadIdx.x;
    int c4cnt = cols >> 2;
    if (i >= rows * c4cnt) return;
    int r = i / c4cnt, c4 = (i - r * c4cnt) * 4;
    float4 v = *(const float4*)(src + (size_t)r * src_ld + c4);
    ushort4 o = { f2bf(v.x), f2bf(v.y), f2bf(v.z), f2bf(v.w) };
    *(ushort4*)(dst + (size_t)r * dst_ld + dcol0 + c4) = o;
}

// decode (i -> unit word) for frag arrays: i indexes 4-byte words
// unit = i>>8; lane = (i>>2)&63; b0 = (i&3)*4; ch=b0>>3; bb=b0&7; q=lane>>4
// k-in-tile = ch*32 + q*8 + bb .. +3 (contiguous)
__global__ void pack_xenc_frag(const float* __restrict__ xenc, const int* __restrict__ len,
                               u8* __restrict__ xef) {
    int i = blockIdx.x * 256 + threadIdx.x;    // 15*2*128*1024/4 = 983040
    if (i >= 983040) return;
    int b0 = (i & 3) * 4;
    int lane = (i >> 2) & 63;
    int unit = i >> 8;
    int rg = unit & 127;
    int tk = unit >> 7;
    int kt = tk & 1, t = tk >> 1;
    int row = rg * 16 + (lane & 15);
    int k = kt * 64 + (b0 >> 3) * 32 + (lane >> 4) * 8 + (b0 & 7);
    int dir = row >> 10, bidx = row & 1023;
    int tt = t;
    if (dir) { int ri = len[bidx] - 1 - t; tt = ri < 0 ? 0 : (ri > T_ - 1 ? T_ - 1 : ri); }
    float4 v = *(const float4*)(xenc + ((size_t)bidx * T_ + tt) * 128 + k);
    unsigned o = f2e4(v.x) | ((unsigned)f2e4(v.y) << 8) |
                 ((unsigned)f2e4(v.z) << 16) | ((unsigned)f2e4(v.w) << 24);
    *(unsigned*)(xef + (size_t)unit * 1024 + lane * 16 + b0) = o;
}

__global__ void pack_xdec_frag(const float* __restrict__ emb, const int* __restrict__ tokens,
                               u8* __restrict__ xdf) {
    int i = blockIdx.x * 256 + threadIdx.x;    // 15*2*64*1024/4 = 491520
    if (i >= 491520) return;
    int b0 = (i & 3) * 4;
    int lane = (i >> 2) & 63;
    int unit = i >> 8;
    int rg = unit & 63;
    int tk = unit >> 6;
    int kt = tk & 1, t = tk >> 1;
    unsigned o = 0;
    if (t > 0) {
        int row = rg * 16 + (lane & 15);
        int k = kt * 64 + (b0 >> 3) * 32 + (lane >> 4) * 8 + (b0 & 7);
        int tok = tokens[(size_t)row * T_ + (t - 1)];
        float4 v = *(const float4*)(emb + (size_t)tok * 128 + k);
        o = f2e4(v.x) | ((unsigned)f2e4(v.y) << 8) |
            ((unsigned)f2e4(v.z) << 16) | ((unsigned)f2e4(v.w) << 24);
    }
    *(unsigned*)(xdf + (size_t)unit * 1024 + lane * 16 + b0) = o;
}

__global__ void pack_wenc_frag(const float* __restrict__ Wih_f, const float* __restrict__ Whh_f,
                               const float* __restrict__ Wih_b, const float* __restrict__ Whh_b,
                               u8* __restrict__ W) {
    int i = blockIdx.x * 256 + threadIdx.x;    // 2*32*18*8*1024/4 = 2359296
    if (i >= 2359296) return;
    int b0 = (i & 3) * 4;
    int lane = (i >> 2) & 63;
    int unit = i >> 8;
    int sub = unit & 7;                        // wc*4+n
    int ktb = unit >> 3;
    int kt = ktb % 18;
    int blk = ktb / 18;
    int bnb = blk & 31, dir = blk >> 5;
    int col = bnb * 128 + (sub >> 2) * 64 + (sub & 3) * 16 + (lane & 15);
    int j = ((col >> 6) << 4) + (col & 15);
    int g = (col >> 4) & 3;
    int srow = g * 1024 + j;
    int k = kt * 64 + (b0 >> 3) * 32 + (lane >> 4) * 8 + (b0 & 7);
    float4 v;
    if (k < 128) {
        const float* s = dir ? Wih_b : Wih_f;
        v = *(const float4*)(s + (size_t)srow * 128 + k);
    } else {
        const float* s = dir ? Whh_b : Whh_f;
        v = *(const float4*)(s + (size_t)srow * 1024 + (k - 128));
    }
    unsigned o = f2e4(v.x) | ((unsigned)f2e4(v.y) << 8) |
                 ((unsigned)f2e4(v.z) << 16) | ((unsigned)f2e4(v.w) << 24);
    *(unsigned*)(W + (size_t)unit * 1024 + lane * 16 + b0) = o;
}

__global__ void pack_wdec_frag(const float* __restrict__ Wi, const float* __restrict__ Wo,
                               const float* __restrict__ Wf, const float* __restrict__ Wg,
                               u8* __restrict__ W) {
    int i = blockIdx.x * 256 + threadIdx.x;    // 32*18*8*1024/4 = 1179648
    if (i >= 1179648) return;
    int b0 = (i & 3) * 4;
    int lane = (i >> 2) & 63;
    int unit = i >> 8;
    int sub = unit & 7;
    int ktb = unit >> 3;
    int kt = ktb % 18;
    int bnb = ktb / 18;
    int col = bnb * 128 + (sub >> 2) * 64 + (sub & 3) * 16 + (lane & 15);
    int j = ((col >> 6) << 4) + (col & 15);
    int g = (col >> 4) & 3;
    const float* s = (g == 0) ? Wi : (g == 1) ? Wo : (g == 2) ? Wf : Wg;
    int k = kt * 64 + (b0 >> 3) * 32 + (lane >> 4) * 8 + (b0 & 7);
    float4 v = *(const float4*)(s + (size_t)j * 1152 + k);
    unsigned o = f2e4(v.x) | ((unsigned)f2e4(v.y) << 8) |
                 ((unsigned)f2e4(v.z) << 16) | ((unsigned)f2e4(v.w) << 24);
    *(unsigned*)(W + (size_t)unit * 1024 + lane * 16 + b0) = o;
}

__global__ void pack_w1_frag(const float* __restrict__ W1, u8* __restrict__ W) {
    int i = blockIdx.x * 256 + threadIdx.x;    // 8*20*8*1024/4 = 327680
    if (i >= 327680) return;
    int b0 = (i & 3) * 4;
    int lane = (i >> 2) & 63;
    int unit = i >> 8;
    int sub = unit & 7;
    int ktb = unit >> 3;
    int kt = ktb % 20;
    int bnb = ktb / 20;
    int col = bnb * 128 + (sub >> 2) * 64 + (sub & 3) * 16 + (lane & 15);   // 0..1023
    int k = kt * 64 + (b0 >> 3) * 32 + (lane >> 4) * 8 + (b0 & 7);
    float4 v = *(const float4*)(W1 + (size_t)col * 1280 + k);
    unsigned o = f2e4(v.x) | ((unsigned)f2e4(v.y) << 8) |
                 ((unsigned)f2e4(v.z) << 16) | ((unsigned)f2e4(v.w) << 24);
    *(unsigned*)(W + (size_t)unit * 1024 + lane * 16 + b0) = o;
}

__global__ void pack_w2_frag(const float* __restrict__ W2, u8* __restrict__ W) {
    int i = blockIdx.x * 256 + threadIdx.x;    // 16*8*1024/4 = 32768
    if (i >= 32768) return;
    int b0 = (i & 3) * 4;
    int lane = (i >> 2) & 63;
    int unit = i >> 8;
    int sub = unit & 7;
    int kt = unit >> 3;
    int col = (sub >> 2) * 64 + (sub & 3) * 16 + (lane & 15);   // 0..127
    unsigned o = 0;
    if (col < V_) {
        int k = kt * 64 + (b0 >> 3) * 32 + (lane >> 4) * 8 + (b0 & 7);
        float4 v = *(const float4*)(W2 + (size_t)col * 1024 + k);
        o = f2e4(v.x) | ((unsigned)f2e4(v.y) << 8) |
            ((unsigned)f2e4(v.z) << 16) | ((unsigned)f2e4(v.w) << 24);
    }
    *(unsigned*)(W + (size_t)unit * 1024 + lane * 16 + b0) = o;
}

// ================= elementwise =================
__global__ void init_zero(ushort* cenc, ushort* cdec, u8* hfA, float* accs) {
    int i = blockIdx.x * 256 + threadIdx.x;   // 2M threads
    if (i < 2 * 1024 * 1024) { cenc[i] = 0; hfA[i] = 0; }
    if (i < 1024 * 1024) cdec[i] = 0;
    if (i < 8) accs[i] = 0.0f;
}

__global__ void latent_ew(const float* __restrict__ ml, const float* __restrict__ bmv,
                          const float* __restrict__ blv, const float* __restrict__ eps,
                          ushort* __restrict__ zb, u8* __restrict__ z8f,
                          float* __restrict__ klacc) {
    int idx = blockIdx.x * 256 + threadIdx.x;   // B*L
    int b = idx >> 7, l = idx & (L_ - 1);
    float mean = ml[(size_t)b * 256 + l] + bmv[l];
    float logv = ml[(size_t)b * 256 + L_ + l] + blv[l];
    float zv = eps[idx] * expf(0.5f * logv) + mean;
    zb[idx] = f2bf(zv);
    // z frag: k = 1152 + l -> tile (l>>6), kp = l&63 (dec RG=64)
    size_t off = ((size_t)(l >> 6) * 64 + (b >> 4)) * 1024 +
                 frag_off(0, l & 63) + (size_t)(b & 15) * 16;
    z8f[off] = f2e4(zv);
    float part = 1.0f + logv - mean * mean - expf(logv);
    for (int offc = 32; offc; offc >>= 1) part += __shfl_down(part, offc);
    __shared__ float s[4];
    int lane = threadIdx.x & 63, wv = threadIdx.x >> 6;
    if (lane == 0) s[wv] = part;
    __syncthreads();
    if (threadIdx.x == 0) atomicAdd(klacc, s[0] + s[1] + s[2] + s[3]);
}

__global__ void finalize_k(const float* accs, float* out) {
    if (threadIdx.x == 0 && blockIdx.x == 0) {
        float kl = -0.5f * accs[3] / (float)B_;
        float amino = accs[0] / (float)B_;
        out[0] = amino + 0.1f * kl;
        out[1] = amino;
        out[2] = kl;
        out[3] = accs[1] / accs[2];
    }
}

// ================= host =================
extern "C" void kernel_launch(void* const* d_in, const int* in_sizes, int n_in,
                              void* d_out, int out_size, void* d_ws, size_t ws_size,
                              hipStream_t stream) {
    (void)in_sizes; (void)n_in; (void)out_size; (void)ws_size;
    const float* x_enc  = (const float*)d_in[0];
    const int*   tokens = (const int*)d_in[1];
    const int*   lengths= (const int*)d_in[2];
    const float* eps    = (const float*)d_in[3];
    const float* emb    = (const float*)d_in[4];
    const float* Wih_f  = (const float*)d_in[5];
    const float* Whh_f  = (const float*)d_in[6];
    const float* b_f    = (const float*)d_in[7];
    const float* Wih_b  = (const float*)d_in[8];
    const float* Whh_b  = (const float*)d_in[9];
    const float* b_b    = (const float*)d_in[10];
    const float* Wm     = (const float*)d_in[11];
    const float* bm     = (const float*)d_in[12];
    const float* Wl     = (const float*)d_in[13];
    const float* bl     = (const float*)d_in[14];
    const float* Wz     = (const float*)d_in[15];
    const float* bz     = (const float*)d_in[16];
    const float* Wi     = (const float*)d_in[17];
    const float* bi     = (const float*)d_in[18];
    const float* Wo     = (const float*)d_in[19];
    const float* bo     = (const float*)d_in[20];
    const float* Wfm    = (const float*)d_in[21];
    const float* bf     = (const float*)d_in[22];
    const float* Wg     = (const float*)d_in[23];
    const float* bg     = (const float*)d_in[24];
    const float* W1     = (const float*)d_in[25];
    const float* b1     = (const float*)d_in[26];
    const float* W2     = (const float*)d_in[27];
    const float* b2     = (const float*)d_in[28];

    float*  ml   = (float*)d_ws;                       // 262144 f32
    float*  accs = ml + 262144;                        // 64
    ushort* cenc = (ushort*)(accs + 64);               // 2M bf16
    ushort* cdec = cenc + 2 * 1024 * 1024;             // 1M bf16
    ushort* hidp = cdec + 1024 * 1024;                 // 2M bf16
    ushort* Wml  = hidp + 2 * 1024 * 1024;             // 256*2048
    ushort* Wzp  = Wml + 256 * 2048;                   // 1024*128
    ushort* zb   = Wzp + 1024 * 128;                   // 1024*128
    u8* xef  = (u8*)(zb + 1024 * 128);                 // 15*2*128*1024
    u8* hfA  = xef + 15 * 2 * 128 * 1024;              // 16*128*1024
    u8* hfB  = hfA + 16 * 128 * 1024;
    u8* xdf  = hfB + 16 * 128 * 1024;                  // 15*2*64*1024
    u8* hdfA = xdf + 15 * 2 * 64 * 1024;               // 16*64*1024
    u8* hdfB = hdfA + 16 * 64 * 1024;
    u8* z8f  = hdfB + 16 * 64 * 1024;                  // 2*64*1024
    u8* h1fA = z8f + 2 * 64 * 1024;                    // 16*64*1024
    u8* h1fB = h1fA + 16 * 64 * 1024;
    u8* WfE  = h1fB + 16 * 64 * 1024;                  // 2*32*18*8*1024
    u8* WfDg = WfE + 2 * 32 * 18 * 8 * 1024;           // 32*18*8*1024
    u8* WfD1 = WfDg + 32 * 18 * 8 * 1024;              // 8*20*8*1024
    u8* WfD2 = WfD1 + 8 * 20 * 8 * 1024;               // 16*8*1024

    init_zero<<<8192, 256, 0, stream>>>(cenc, cdec, hfA, accs);
    pack_wenc_frag<<<9216, 256, 0, stream>>>(Wih_f, Whh_f, Wih_b, Whh_b, WfE);
    pack_wdec_frag<<<4608, 256, 0, stream>>>(Wi, Wo, Wfm, Wg, WfDg);
    pack_w1_frag<<<1280, 256, 0, stream>>>(W1, WfD1);
    pack_w2_frag<<<128, 256, 0, stream>>>(W2, WfD2);
    pack_cols<<<256, 256, 0, stream>>>(Wm, 2048, Wml, 2048, 0, L_, 2048);
    pack_cols<<<256, 256, 0, stream>>>(Wl, 2048, Wml + L_ * 2048, 2048, 0, L_, 2048);
    pack_cols<<<128, 256, 0, stream>>>(Wz, L_, Wzp, L_, 0, H_, L_);
    pack_xenc_frag<<<3840, 256, 0, stream>>>(x_enc, lengths, xef);
    pack_xdec_frag<<<1920, 256, 0, stream>>>(emb, tokens, xdf);

    // ---- encoder: fp8 reg-direct, grid (32, 32) ----
    {
        const u8* hc = hfA; u8* hn = hfB;
        for (int t = 0; t < T_; ++t) {
            gemm_reg<<<dim3(32, 32), 256, 0, stream>>>(
                AEnc{ xef + (size_t)t * 2 * 131072, hc, 0 }, WEnc{ WfE },
                EpiEnc8{ b_f, b_b, lengths, t, cenc, hc, hn, hidp });
            const u8* tmp = hn; hn = (u8*)hc; hc = tmp;
        }
    }
    // ---- latents (bf16 LDS path) ----
    gemm_t64<<<dim3(2, 16), 256, 0, stream>>>(
        ALdPlain{ hidp, 2048, 2048 }, WLdPlain{ Wml, 2048 }, EpiStoreF32{ ml, 256 });
    latent_ew<<<512, 256, 0, stream>>>(ml, bm, bl, eps, zb, z8f, &accs[3]);
    gemm_t64<<<dim3(8, 16), 256, 0, stream>>>(
        ALdPlain{ zb, 128, 128 }, WLdPlain{ Wzp, 128 }, EpiBiasF8Frag{ hdfA, bz });

    // ---- decoder: fp8 reg-direct, scores(t-1) fused ----
    {
        const u8* dc = hdfA; u8* dn = hdfB;
        for (int t = 0; t < T_; ++t) {
            u8* h1c = (t & 1) ? h1fB : h1fA;
            const u8* h1p = (t & 1) ? h1fA : h1fB;
            dim3 grid(t == 0 ? 40 : 41, 16);
            gemm_reg<<<grid, 256, 0, stream>>>(
                ADec{ xdf + (size_t)t * 2 * 65536, dc, z8f, h1p, 0 },
                WDec{ WfDg, WfD1, WfD2 },
                EpiDec8{ bi, bo, bf, bg, b1, b2, cdec, dn, h1c, tokens, lengths, t, accs });
            const u8* tmp = dn; dn = (u8*)dc; dc = tmp;
        }
        // trailing scores for t=14 (hid1 written at t=14 -> h1fA)
        gemm_reg<<<dim3(1, 16), 256, 0, stream>>>(
            ADec{ xdf, dc, z8f, h1fA, 5120 },
            WDec{ WfDg, WfD1, WfD2 },
            EpiDec8{ bi, bo, bf, bg, b1, b2, cdec, hdfB, h1fB, tokens, lengths, T_, accs });
    }

    finalize_k<<<1, 64, 0, stream>>>(accs, (float*)d_out);
}